// Round 7
// baseline (311.350 us; speedup 1.0000x reference)
//
#include <hip/hip_runtime.h>

#define HH 128
#define NT 512
#define PT 256

typedef float  f32x4  __attribute__((ext_vector_type(4)));
typedef short  bf16x8 __attribute__((ext_vector_type(8)));

static __device__ __forceinline__ unsigned short bf16_rne(float f){
  unsigned int u = __float_as_uint(f);
  unsigned int r = u + 0x7fffu + ((u >> 16) & 1u);
  return (unsigned short)(r >> 16);
}
static __device__ __forceinline__ unsigned short bf16_trunc(float f){
  return (unsigned short)(__float_as_uint(f) >> 16);
}
static __device__ __forceinline__ float bf16_to_f(unsigned short s){
  return __uint_as_float(((unsigned int)s) << 16);
}

// interleaved split storage: low16 = hi-bf16, high16 = lo-bf16
static __device__ __forceinline__ unsigned int pack_hl(float v){
  unsigned int u = __float_as_uint(v);
  unsigned int rh = (u + 0x7fffu + ((u >> 16) & 1u)) & 0xffff0000u;
  float resid = v - __uint_as_float(rh);
  unsigned int lo = __float_as_uint(resid) & 0xffff0000u;
  return (rh >> 16) | lo;
}
static __device__ __forceinline__ float unpack_hl(unsigned int u){
  return __uint_as_float(u << 16) + __uint_as_float(u & 0xffff0000u);
}

// fast saturating sigmoid/tanh via v_exp_f32 + v_rcp_f32
__device__ __forceinline__ float sigf(float x){
  float t = __builtin_amdgcn_exp2f(-1.44269504089f * x);
  return __builtin_amdgcn_rcpf(1.f + t);
}
__device__ __forceinline__ float tanhf_(float x){
  float t = __builtin_amdgcn_exp2f(2.88539008178f * x);
  return 1.f - 2.f*__builtin_amdgcn_rcpf(t + 1.f);
}

// Pack W into MFMA-B-fragment order, split bf16 hi/lo.
// Pack index: (((wp*8 + q*2 + ft)*4 + kc)*64 + lane)*8 + j
//   g = q*128 + wp*32 + ft*16 + (lane&15);  k = kc*32 + (lane>>4)*8 + j
__global__ __launch_bounds__(PT) void prep_pack(
    const float* __restrict__ W,
    unsigned short* __restrict__ pEh, unsigned short* __restrict__ pEl,
    unsigned short* __restrict__ pLh, unsigned short* __restrict__ pLl)
{
  int idx = blockIdx.x*PT + threadIdx.x;     // 0..8191
  int l  = idx & 63;
  int kc = (idx >> 6) & 3;
  int gl = (idx >> 8) & 7;
  int wp = (idx >> 11);                      // 0..3
  int q  = gl >> 1, ft = gl & 1;
  int g  = q*128 + wp*32 + ft*16 + (l & 15);
  int kbase = kc*32 + (l >> 4)*8;

  unsigned short eh[8], el[8], lh[8], ll[8];
#pragma unroll
  for (int j = 0; j < 8; ++j){
    int k = kbase + j;
    float w0 = W[g*256 + k];
    float w1 = W[g*256 + 128 + k];
    float we = w0 + 0.5f*w1;
    unsigned short h0 = bf16_rne(we);
    eh[j] = h0; el[j] = bf16_trunc(we - bf16_to_f(h0));
    unsigned short h1 = bf16_rne(w1);
    lh[j] = h1; ll[j] = bf16_trunc(w1 - bf16_to_f(h1));
  }
  long base = (long)idx*8;
  *(bf16x8*)&pEh[base] = *(bf16x8*)eh;
  *(bf16x8*)&pEl[base] = *(bf16x8*)el;
  *(bf16x8*)&pLh[base] = *(bf16x8*)lh;
  *(bf16x8*)&pLl[base] = *(bf16x8*)ll;
}

// One tree level, LDS-dbuf staged, MT_*16-row tiles, 8 waves.
// Wave w owns feats [w*16,(w+1)*16) x all gate types.
// LEAF=1: input fp32 x (cc=0, q=0 skipped). LEAF=0: input interleaved planes.
// Output: pair-sum interleaved planes (h and c).
template<int LEAF, int MT_>
__global__ __launch_bounds__(NT, 4) void lvl_mfma(
    const float* __restrict__ x_leaf,
    const unsigned int* __restrict__ hP, const unsigned int* __restrict__ cP,
    const unsigned short* __restrict__ packH, const unsigned short* __restrict__ packL,
    const float* __restrict__ bias,
    unsigned int* __restrict__ hO, unsigned int* __restrict__ cO,
    int ntiles)
{
  constexpr int ROWS = MT_*16;
  constexpr int EPT  = ROWS*HH/NT;          // elems per thread in stage (8 or 16)
  constexpr int RS   = (EPT == 16) ? 3 : 4; // threads per row shift
  __shared__ unsigned short AsH[2][ROWS][HH+8];
  __shared__ unsigned short AsL[2][ROWS][HH+8];

  const int t = threadIdx.x;
  const int w = t >> 6, l = t & 63;
  const int a = l >> 4, fcol = l & 15, feat = w*16 + fcol;
  constexpr int Q0 = LEAF ? 1 : 0;

  float B4[4];
#pragma unroll
  for (int q = Q0; q < 4; ++q) B4[q] = bias[q*HH + feat];

  auto stage = [&](int buf, int tile){
    int row = t >> RS;
    int c0  = (t & ((1<<RS)-1))*EPT;
#pragma unroll
    for (int b8 = 0; b8 < EPT/8; ++b8){
      int cc0 = c0 + b8*8;
      long base = ((long)tile*ROWS + row)*HH + cc0;
      unsigned int hp[4], lp[4];
      if (LEAF){
        float v[8];
        *(float4*)&v[0] = *(const float4*)&x_leaf[base];
        *(float4*)&v[4] = *(const float4*)&x_leaf[base + 4];
#pragma unroll
        for (int p = 0; p < 4; ++p){
          unsigned int u0 = __float_as_uint(v[2*p]);
          unsigned int u1 = __float_as_uint(v[2*p+1]);
          unsigned int r0 = u0 + 0x7fffu + ((u0>>16)&1u);
          unsigned int r1 = u1 + 0x7fffu + ((u1>>16)&1u);
          float l0 = v[2*p]   - __uint_as_float(r0 & 0xffff0000u);
          float l1 = v[2*p+1] - __uint_as_float(r1 & 0xffff0000u);
          hp[p] = __builtin_amdgcn_perm(r1, r0, 0x07060302u);
          lp[p] = __builtin_amdgcn_perm(__float_as_uint(l1), __float_as_uint(l0), 0x07060302u);
        }
      } else {
        unsigned int u[8];
        *(uint4*)&u[0] = *(const uint4*)&hP[base];
        *(uint4*)&u[4] = *(const uint4*)&hP[base + 4];
#pragma unroll
        for (int p = 0; p < 4; ++p){
          hp[p] = __builtin_amdgcn_perm(u[2*p+1], u[2*p], 0x05040100u);
          lp[p] = __builtin_amdgcn_perm(u[2*p+1], u[2*p], 0x07060302u);
        }
      }
      uint4 hq = {hp[0], hp[1], hp[2], hp[3]};
      uint4 lq = {lp[0], lp[1], lp[2], lp[3]};
      *(uint4*)&AsH[buf][row][cc0] = hq;
      *(uint4*)&AsL[buf][row][cc0] = lq;
    }
  };

  int tile = blockIdx.x;
  if (tile < ntiles) stage(0, tile);
  __syncthreads();
  int buf = 0;

  for (; tile < ntiles; tile += gridDim.x){
    int nxt = tile + gridDim.x;
    if (nxt < ntiles) stage(buf^1, nxt);

    // preload cc (interleaved) for the epilogue
    unsigned int ccu[MT_][4];
    if (!LEAF){
#pragma unroll
      for (int mt = 0; mt < MT_; ++mt)
#pragma unroll
        for (int rr = 0; rr < 4; ++rr)
          ccu[mt][rr] = cP[((long)tile*ROWS + mt*16 + a*4 + rr)*HH + feat];
    }

    f32x4 acc[MT_][4];
#pragma unroll
    for (int mt = 0; mt < MT_; ++mt)
#pragma unroll
      for (int q = Q0; q < 4; ++q) acc[mt][q] = (f32x4)(0.f);

#pragma unroll
    for (int kc = 0; kc < 4; ++kc){
      bf16x8 aH[MT_], aL[MT_];
#pragma unroll
      for (int mt = 0; mt < MT_; ++mt){
        int row = mt*16 + fcol;
        int co  = kc*32 + a*8;
        aH[mt] = *(const bf16x8*)&AsH[buf][row][co];
        aL[mt] = *(const bf16x8*)&AsL[buf][row][co];
      }
      bf16x8 bH[4], bL[4];
#pragma unroll
      for (int q = Q0; q < 4; ++q){
        long off = ((long)((((w>>1)*8) + q*2 + (w&1))*4 + kc)*64 + l)*8;
        bH[q] = *(const bf16x8*)&packH[off];
        bL[q] = *(const bf16x8*)&packL[off];
      }
      // part-major: groups aH*bH, aL*bH, aH*bL (bH dead after group 2)
#pragma unroll
      for (int q = Q0; q < 4; ++q)
#pragma unroll
        for (int mt = 0; mt < MT_; ++mt)
          acc[mt][q] = __builtin_amdgcn_mfma_f32_16x16x32_bf16(aH[mt], bH[q], acc[mt][q], 0, 0, 0);
#pragma unroll
      for (int q = Q0; q < 4; ++q)
#pragma unroll
        for (int mt = 0; mt < MT_; ++mt)
          acc[mt][q] = __builtin_amdgcn_mfma_f32_16x16x32_bf16(aL[mt], bH[q], acc[mt][q], 0, 0, 0);
#pragma unroll
      for (int q = Q0; q < 4; ++q)
#pragma unroll
        for (int mt = 0; mt < MT_; ++mt)
          acc[mt][q] = __builtin_amdgcn_mfma_f32_16x16x32_bf16(aH[mt], bL[q], acc[mt][q], 0, 0, 0);
    }

    // epilogue: LSTM cell, pair-sum, pack interleaved
#pragma unroll
    for (int mt = 0; mt < MT_; ++mt){
      float hv[4], cv[4];
#pragma unroll
      for (int rr = 0; rr < 4; ++rr){
        float cc = 0.f;
        if (!LEAF) cc = unpack_hl(ccu[mt][rr]);
        float iv = acc[mt][1][rr] + B4[1];
        float gv = acc[mt][2][rr] + B4[2];
        float ov = acc[mt][3][rr] + B4[3];
        float c;
        if (LEAF){
          c = sigf(iv)*tanhf_(gv);
        } else {
          float fv = acc[mt][0][rr] + B4[0];
          c = sigf(fv)*cc + sigf(iv)*tanhf_(gv);
        }
        float h = sigf(ov)*tanhf_(c);
        hv[rr] = h; cv[rr] = c;
      }
#pragma unroll
      for (int p = 0; p < 2; ++p){
        long prow = (long)tile*(ROWS/2) + mt*8 + a*2 + p;
        hO[prow*HH + feat] = pack_hl(hv[2*p] + hv[2*p+1]);
        cO[prow*HH + feat] = pack_hl(cv[2*p] + cv[2*p+1]);
      }
    }
    __syncthreads();
    buf ^= 1;
  }
}

// Multi-level tail block. INPLANES=1: stage ROWS0 pair-rows from interleaved
// planes. INPLANES=0: stage 2*ROWS0 raw f32 h,c rows pair-summed. NLEV levels
// in LDS. FINAL=1 writes root h; else one f32 h,c node per block.
template<int ROWS0, int NLEV, int INPLANES, int FINAL>
__global__ __launch_bounds__(NT, 2) void treeblk2(
    const unsigned int* __restrict__ hPl, const unsigned int* __restrict__ cPl,
    const float* __restrict__ hraw, const float* __restrict__ craw,
    const unsigned short* __restrict__ packH, const unsigned short* __restrict__ packL,
    const float* __restrict__ bias,
    float* __restrict__ h_out, float* __restrict__ c_out,
    float* __restrict__ root_out)
{
  constexpr int MT = ROWS0/16;
  __shared__ float Asum[ROWS0][132];
  __shared__ float Csum[ROWS0][132];

  const int t = threadIdx.x;
  const long blk = blockIdx.x;
  const int w = t >> 6, l = t & 63;
  const int a = l >> 4, fcol = l & 15, feat = w*16 + fcol;

  // ---- stage ----
  if constexpr (INPLANES){
    constexpr int EPT = ROWS0*HH/NT;        // 8 for ROWS0=32
    int row = t >> 4, c0 = (t & 15)*EPT;
    long base = (blk*ROWS0 + row)*(long)HH + c0;
#pragma unroll
    for (int j = 0; j < EPT; ++j){
      Asum[row][c0+j] = unpack_hl(hPl[base+j]);
      Csum[row][c0+j] = unpack_hl(cPl[base+j]);
    }
  } else {
    int row = t >> 3, c0 = (t & 7)*16;
    long g = (blk*2*ROWS0 + 2*row)*(long)HH + c0;
#pragma unroll
    for (int i = 0; i < 4; ++i){
      float4 x = *(const float4*)&hraw[g + 4*i];
      float4 y = *(const float4*)&hraw[g + HH + 4*i];
      float4 s; s.x=x.x+y.x; s.y=x.y+y.y; s.z=x.z+y.z; s.w=x.w+y.w;
      *(float4*)&Asum[row][c0 + 4*i] = s;
      float4 cx = *(const float4*)&craw[g + 4*i];
      float4 cy = *(const float4*)&craw[g + HH + 4*i];
      float4 cs4; cs4.x=cx.x+cy.x; cs4.y=cx.y+cy.y; cs4.z=cx.z+cy.z; cs4.w=cx.w+cy.w;
      *(float4*)&Csum[row][c0 + 4*i] = cs4;
    }
  }

  bf16x8 rbH[4][4], rbL[4][4];
#pragma unroll
  for (int q = 0; q < 4; ++q)
#pragma unroll
    for (int kc = 0; kc < 4; ++kc){
      long off = ((long)((((w>>1)*8) + q*2 + (w&1))*4 + kc)*64 + l)*8;
      rbH[q][kc] = *(const bf16x8*)&packH[off];
      rbL[q][kc] = *(const bf16x8*)&packL[off];
    }
  float B4[4];
#pragma unroll
  for (int q = 0; q < 4; ++q) B4[q] = bias[q*HH + feat];

  __syncthreads();

#pragma unroll
  for (int lv = 0; lv < NLEV; ++lv){
    const int rows  = ROWS0 >> lv;
    const int tiles = (rows >= 16) ? (rows/16) : 1;
    float hv[MT][4], cv[MT][4];

#pragma unroll
    for (int mt = 0; mt < MT; ++mt){
      if (mt >= tiles) continue;
      bf16x8 aH[4], aL[4];
#pragma unroll
      for (int kc = 0; kc < 4; ++kc){
        const float* ap = &Asum[mt*16 + fcol][kc*32 + a*8];
        float av[8];
        *(float4*)&av[0] = *(const float4*)&ap[0];
        *(float4*)&av[4] = *(const float4*)&ap[4];
        unsigned int hp[4], lp[4];
#pragma unroll
        for (int p = 0; p < 4; ++p){
          unsigned int u0 = __float_as_uint(av[2*p]);
          unsigned int u1 = __float_as_uint(av[2*p+1]);
          unsigned int r0 = u0 + 0x7fffu + ((u0>>16)&1u);
          unsigned int r1 = u1 + 0x7fffu + ((u1>>16)&1u);
          float l0 = av[2*p]   - __uint_as_float(r0 & 0xffff0000u);
          float l1 = av[2*p+1] - __uint_as_float(r1 & 0xffff0000u);
          hp[p] = __builtin_amdgcn_perm(r1, r0, 0x07060302u);
          lp[p] = __builtin_amdgcn_perm(__float_as_uint(l1), __float_as_uint(l0), 0x07060302u);
        }
        uint4 hq = {hp[0], hp[1], hp[2], hp[3]};
        uint4 lq = {lp[0], lp[1], lp[2], lp[3]};
        aH[kc] = *(bf16x8*)&hq;
        aL[kc] = *(bf16x8*)&lq;
      }
      f32x4 acc[4];
#pragma unroll
      for (int q = 0; q < 4; ++q) acc[q] = (f32x4)(0.f);
#pragma unroll
      for (int kc = 0; kc < 4; ++kc){
#pragma unroll
        for (int q = 0; q < 4; ++q)
          acc[q] = __builtin_amdgcn_mfma_f32_16x16x32_bf16(aH[kc], rbH[q][kc], acc[q], 0, 0, 0);
#pragma unroll
        for (int q = 0; q < 4; ++q)
          acc[q] = __builtin_amdgcn_mfma_f32_16x16x32_bf16(aL[kc], rbH[q][kc], acc[q], 0, 0, 0);
#pragma unroll
        for (int q = 0; q < 4; ++q)
          acc[q] = __builtin_amdgcn_mfma_f32_16x16x32_bf16(aH[kc], rbL[q][kc], acc[q], 0, 0, 0);
      }
#pragma unroll
      for (int rr = 0; rr < 4; ++rr){
        int n = mt*16 + a*4 + rr;
        float ccv = Csum[n][feat];
        float fv = acc[0][rr] + B4[0];
        float iv = acc[1][rr] + B4[1];
        float gv = acc[2][rr] + B4[2];
        float ov = acc[3][rr] + B4[3];
        float c = sigf(fv)*ccv + sigf(iv)*tanhf_(gv);
        float h = sigf(ov)*tanhf_(c);
        hv[mt][rr] = h; cv[mt][rr] = c;
      }
    }
    __syncthreads();

    if (lv < NLEV-1){
#pragma unroll
      for (int mt = 0; mt < MT; ++mt){
        if (mt >= tiles) continue;
#pragma unroll
        for (int p = 0; p < 2; ++p){
          int n0 = mt*16 + a*4 + 2*p;
          if (n0 < rows){
            int prow = n0 >> 1;
            Asum[prow][feat] = hv[mt][2*p] + hv[mt][2*p+1];
            Csum[prow][feat] = cv[mt][2*p] + cv[mt][2*p+1];
          }
        }
      }
      __syncthreads();
    } else if (FINAL){
      if (a == 0) root_out[feat] = hv[0][0];
    } else {
      if (a == 0){
        h_out[blk*HH + feat] = hv[0][0];
        c_out[blk*HH + feat] = cv[0][0];
      }
    }
  }
}

extern "C" void kernel_launch(void* const* d_in, const int* in_sizes, int n_in,
                              void* d_out, int out_size, void* d_ws, size_t ws_size,
                              hipStream_t stream){
  const float* leaf = (const float*)d_in[0];   // 131072 x 128 f32
  const float* W    = (const float*)d_in[1];   // 512 x 256 f32
  const float* bias = (const float*)d_in[2];   // 512 f32
  float* out = (float*)d_out;                  // 128 f32

  unsigned short* pEh = (unsigned short*)d_ws;  // 65536 shorts each
  unsigned short* pEl = pEh + 65536;
  unsigned short* pLh = pEl + 65536;
  unsigned short* pLl = pLh + 65536;
  unsigned int* hA = (unsigned int*)(pLl + 65536);  // 2^16 x 128 u32
  unsigned int* cA = hA + (long)(1<<16)*HH;
  unsigned int* hB = cA + (long)(1<<16)*HH;         // 2^15 x 128 u32
  unsigned int* cB = hB + (long)(1<<15)*HH;
  float* h128 = (float*)(cB + (long)(1<<15)*HH);    // 128 x 128 f32
  float* c128 = h128 + 128*HH;

  prep_pack<<<32, PT, 0, stream>>>(W, pEh, pEl, pLh, pLl);

  // leaf: 2^17 nodes (64-row tiles) -> 2^16 pair-rows
  lvl_mfma<1,4><<<512, NT, 0, stream>>>(leaf, nullptr, nullptr, pLh, pLl, bias, hA, cA, 2048);
  // internal levels (32-row tiles): 2^16 -> 2^15 -> 2^14 -> 2^13 -> 2^12 pair-rows
  lvl_mfma<0,2><<<512, NT, 0, stream>>>(nullptr, hA, cA, pEh, pEl, bias, hB, cB, 2048);
  lvl_mfma<0,2><<<512, NT, 0, stream>>>(nullptr, hB, cB, pEh, pEl, bias, hA, cA, 1024);
  lvl_mfma<0,2><<<512, NT, 0, stream>>>(nullptr, hA, cA, pEh, pEl, bias, hB, cB, 512);
  lvl_mfma<0,2><<<256, NT, 0, stream>>>(nullptr, hB, cB, pEh, pEl, bias, hA, cA, 256);
  // tail: 2^12 pair-rows -> 128 nodes (6 levels/block) -> root (7 levels)
  treeblk2<32,6,1,0><<<128, NT, 0, stream>>>(hA, cA, nullptr, nullptr,
                                             pEh, pEl, bias, h128, c128, nullptr);
  treeblk2<64,7,0,1><<<1, NT, 0, stream>>>(nullptr, nullptr, h128, c128,
                                           pEh, pEl, bias, nullptr, nullptr, out);

  (void)in_sizes; (void)n_in; (void)out_size; (void)ws_size;
}

// Round 8
// 142.929 us; speedup vs baseline: 2.1784x; 2.1784x over previous
//
#include <hip/hip_runtime.h>

#define HH 128
#define NT 512
#define PT 256

typedef float  f32x4  __attribute__((ext_vector_type(4)));
typedef short  bf16x8 __attribute__((ext_vector_type(8)));

static __device__ __forceinline__ unsigned short bf16_rne(float f){
  unsigned int u = __float_as_uint(f);
  unsigned int r = u + 0x7fffu + ((u >> 16) & 1u);
  return (unsigned short)(r >> 16);
}
static __device__ __forceinline__ unsigned short bf16_trunc(float f){
  return (unsigned short)(__float_as_uint(f) >> 16);
}
static __device__ __forceinline__ float bf16_to_f(unsigned short s){
  return __uint_as_float(((unsigned int)s) << 16);
}
// split two fp32 into packed hi-bf16 u32 and lo-bf16 u32 (elem0 in low16)
static __device__ __forceinline__ void split2(float x0, float x1,
                                              unsigned int& hp, unsigned int& lp){
  unsigned int u0 = __float_as_uint(x0), u1 = __float_as_uint(x1);
  unsigned int r0 = u0 + 0x7fffu + ((u0>>16)&1u);
  unsigned int r1 = u1 + 0x7fffu + ((u1>>16)&1u);
  float l0 = x0 - __uint_as_float(r0 & 0xffff0000u);
  float l1 = x1 - __uint_as_float(r1 & 0xffff0000u);
  hp = __builtin_amdgcn_perm(r1, r0, 0x07060302u);
  lp = __builtin_amdgcn_perm(__float_as_uint(l1), __float_as_uint(l0), 0x07060302u);
}

__device__ __forceinline__ float sigf(float x){
  float t = __builtin_amdgcn_exp2f(-1.44269504089f * x);
  return __builtin_amdgcn_rcpf(1.f + t);
}
__device__ __forceinline__ float tanhf_(float x){
  float t = __builtin_amdgcn_exp2f(2.88539008178f * x);
  return 1.f - 2.f*__builtin_amdgcn_rcpf(t + 1.f);
}

// Pack W into MFMA-B-fragment order, split bf16 hi/lo.
// Pack index: (((wp*8 + q*2 + ft)*4 + kc)*64 + lane)*8 + j
//   g = q*128 + wp*32 + ft*16 + (lane&15);  k = kc*32 + (lane>>4)*8 + j
__global__ __launch_bounds__(PT) void prep_pack(
    const float* __restrict__ W,
    unsigned short* __restrict__ pEh, unsigned short* __restrict__ pEl,
    unsigned short* __restrict__ pLh, unsigned short* __restrict__ pLl)
{
  int idx = blockIdx.x*PT + threadIdx.x;     // 0..8191
  int l  = idx & 63;
  int kc = (idx >> 6) & 3;
  int gl = (idx >> 8) & 7;
  int wp = (idx >> 11);                      // 0..3
  int q  = gl >> 1, ft = gl & 1;
  int g  = q*128 + wp*32 + ft*16 + (l & 15);
  int kbase = kc*32 + (l >> 4)*8;

  unsigned short eh[8], el[8], lh[8], ll[8];
#pragma unroll
  for (int j = 0; j < 8; ++j){
    int k = kbase + j;
    float w0 = W[g*256 + k];
    float w1 = W[g*256 + 128 + k];
    float we = w0 + 0.5f*w1;
    unsigned short h0 = bf16_rne(we);
    eh[j] = h0; el[j] = bf16_trunc(we - bf16_to_f(h0));
    unsigned short h1 = bf16_rne(w1);
    lh[j] = h1; ll[j] = bf16_trunc(w1 - bf16_to_f(h1));
  }
  long base = (long)idx*8;
  *(bf16x8*)&pEh[base] = *(bf16x8*)eh;
  *(bf16x8*)&pEl[base] = *(bf16x8*)el;
  *(bf16x8*)&pLh[base] = *(bf16x8*)lh;
  *(bf16x8*)&pLl[base] = *(bf16x8*)ll;
}

// ---------------- leaf kernel: L0 only, resident leaf-B (96 VGPR) ----------
__global__ __launch_bounds__(NT, 2) void leafK(
    const float* __restrict__ x_leaf,
    const unsigned short* __restrict__ pLh, const unsigned short* __restrict__ pLl,
    const float* __restrict__ bias,
    unsigned short* __restrict__ HpO, unsigned short* __restrict__ LpO,
    float* __restrict__ csO, int ntiles)
{
  __shared__ unsigned short AsH[2][32*HH];
  __shared__ unsigned short AsL[2][32*HH];

  const int t = threadIdx.x, w = t>>6, l = t&63;
  const int a = l>>4, fcol = l&15, feat = w*16 + fcol;

  // resident leaf-B (gates i,g,o = q 1..3)
  bf16x8 rbH[3][4], rbL[3][4];
#pragma unroll
  for (int qq = 0; qq < 3; ++qq)
#pragma unroll
    for (int kc = 0; kc < 4; ++kc){
      long off = ((long)((((w>>1)*8) + (qq+1)*2 + (w&1))*4 + kc)*64 + l)*8;
      rbH[qq][kc] = *(const bf16x8*)&pLh[off];
      rbL[qq][kc] = *(const bf16x8*)&pLl[off];
    }
  const float Bi = bias[HH + feat], Bg = bias[2*HH + feat], Bo = bias[3*HH + feat];

  const int srow = t>>4, sci = t&15;
  float sv[8];
  auto sload = [&](int tile){
    long base = ((long)tile*32 + srow)*HH + sci*8;
    *(float4*)&sv[0] = *(const float4*)&x_leaf[base];
    *(float4*)&sv[4] = *(const float4*)&x_leaf[base+4];
  };
  auto swrite = [&](int buf){
    unsigned int hp[4], lp[4];
#pragma unroll
    for (int p = 0; p < 4; ++p) split2(sv[2*p], sv[2*p+1], hp[p], lp[p]);
    uint4 hq = {hp[0],hp[1],hp[2],hp[3]};
    uint4 lq = {lp[0],lp[1],lp[2],lp[3]};
    int off = srow*256 + ((sci*16) ^ ((srow&7)<<4));
    *(uint4*)((char*)&AsH[buf][0] + off) = hq;
    *(uint4*)((char*)&AsL[buf][0] + off) = lq;
  };

  int tile = blockIdx.x;
  if (tile < ntiles){ sload(tile); swrite(0); }
  __syncthreads();
  int buf = 0;

  for (; tile < ntiles; tile += gridDim.x){
    int nxt = tile + gridDim.x;
    bool have = nxt < ntiles;
    if (have) sload(nxt);   // loads in flight under MFMA

    f32x4 acc[2][3];
#pragma unroll
    for (int mt = 0; mt < 2; ++mt)
#pragma unroll
      for (int qq = 0; qq < 3; ++qq) acc[mt][qq] = (f32x4)(0.f);

#pragma unroll
    for (int kc = 0; kc < 4; ++kc){
      bf16x8 aH[2], aL[2];
#pragma unroll
      for (int mt = 0; mt < 2; ++mt){
        int row = mt*16 + fcol;
        int off = row*256 + ((kc*64 + a*16) ^ ((row&7)<<4));
        aH[mt] = *(const bf16x8*)((const char*)&AsH[buf][0] + off);
        aL[mt] = *(const bf16x8*)((const char*)&AsL[buf][0] + off);
      }
#pragma unroll
      for (int qq = 0; qq < 3; ++qq)
#pragma unroll
        for (int mt = 0; mt < 2; ++mt)
          acc[mt][qq] = __builtin_amdgcn_mfma_f32_16x16x32_bf16(aH[mt], rbH[qq][kc], acc[mt][qq], 0, 0, 0);
#pragma unroll
      for (int qq = 0; qq < 3; ++qq)
#pragma unroll
        for (int mt = 0; mt < 2; ++mt)
          acc[mt][qq] = __builtin_amdgcn_mfma_f32_16x16x32_bf16(aL[mt], rbH[qq][kc], acc[mt][qq], 0, 0, 0);
#pragma unroll
      for (int qq = 0; qq < 3; ++qq)
#pragma unroll
        for (int mt = 0; mt < 2; ++mt)
          acc[mt][qq] = __builtin_amdgcn_mfma_f32_16x16x32_bf16(aH[mt], rbL[qq][kc], acc[mt][qq], 0, 0, 0);
    }

    // epilogue (cc = 0): c = sig(i)tanh(g); h = sig(o)tanh(c); pair-sum planes
#pragma unroll
    for (int mt = 0; mt < 2; ++mt){
      float hv[4], cv[4];
#pragma unroll
      for (int rr = 0; rr < 4; ++rr){
        float iv = acc[mt][0][rr] + Bi;
        float gv = acc[mt][1][rr] + Bg;
        float ov = acc[mt][2][rr] + Bo;
        float c = sigf(iv)*tanhf_(gv);
        float h = sigf(ov)*tanhf_(c);
        hv[rr] = h; cv[rr] = c;
      }
#pragma unroll
      for (int p = 0; p < 2; ++p){
        long prow = (long)tile*16 + mt*8 + a*2 + p;
        float hs = hv[2*p] + hv[2*p+1];
        unsigned short hi = bf16_rne(hs);
        HpO[prow*HH + feat] = hi;
        LpO[prow*HH + feat] = bf16_trunc(hs - bf16_to_f(hi));
        csO[prow*HH + feat] = cv[2*p] + cv[2*p+1];
      }
    }

    if (have) swrite(buf^1);
    __syncthreads();
    buf ^= 1;
  }
}

// ---------------- fused 2-level internal kernel, resident eff-B ------------
// Per tile: 32 input pair-rows -> level A (32 nodes, MFMA-0) -> pair sums in
// LDS -> level B (16 nodes, MFMA-1) -> 8 output pair-rows. Same B both levels.
__global__ __launch_bounds__(NT, 2) void fuse2(
    const unsigned short* __restrict__ hPH, const unsigned short* __restrict__ hPL,
    const float* __restrict__ cP,
    const unsigned short* __restrict__ pEh, const unsigned short* __restrict__ pEl,
    const float* __restrict__ bias,
    unsigned short* __restrict__ HpO, unsigned short* __restrict__ LpO,
    float* __restrict__ csO, int ntiles)
{
  __shared__ unsigned short AsH[2][32*HH];
  __shared__ unsigned short AsL[2][32*HH];
  __shared__ float HsF[16*HH];
  __shared__ float CsF[16*HH];

  const int t = threadIdx.x, w = t>>6, l = t&63;
  const int a = l>>4, fcol = l&15, feat = w*16 + fcol;

  bf16x8 rbH[4][4], rbL[4][4];
#pragma unroll
  for (int q = 0; q < 4; ++q)
#pragma unroll
    for (int kc = 0; kc < 4; ++kc){
      long off = ((long)((((w>>1)*8) + q*2 + (w&1))*4 + kc)*64 + l)*8;
      rbH[q][kc] = *(const bf16x8*)&pEh[off];
      rbL[q][kc] = *(const bf16x8*)&pEl[off];
    }
  float B4[4];
#pragma unroll
  for (int q = 0; q < 4; ++q) B4[q] = bias[q*HH + feat];

  const int srow = t>>4, sci = t&15;
  bf16x8 svH, svL;
  auto sload = [&](int tile){
    long base = ((long)tile*32 + srow)*HH + sci*8;
    svH = *(const bf16x8*)&hPH[base];
    svL = *(const bf16x8*)&hPL[base];
  };
  auto swrite = [&](int buf){
    int off = srow*256 + ((sci*16) ^ ((srow&7)<<4));
    *(bf16x8*)((char*)&AsH[buf][0] + off) = svH;
    *(bf16x8*)((char*)&AsL[buf][0] + off) = svL;
  };

  int tile = blockIdx.x;
  if (tile < ntiles){ sload(tile); swrite(0); }
  __syncthreads();
  int buf = 0;

  for (; tile < ntiles; tile += gridDim.x){
    int nxt = tile + gridDim.x;
    bool have = nxt < ntiles;

    // cc for level-A epilogue (scattered 4B, issue early to hide latency)
    float cc0[2][4];
#pragma unroll
    for (int mt = 0; mt < 2; ++mt)
#pragma unroll
      for (int rr = 0; rr < 4; ++rr)
        cc0[mt][rr] = cP[((long)tile*32 + mt*16 + a*4 + rr)*HH + feat];

    if (have) sload(nxt);

    // ---- MFMA-0: level A over 32 rows ----
    f32x4 acc0[2][4];
#pragma unroll
    for (int mt = 0; mt < 2; ++mt)
#pragma unroll
      for (int q = 0; q < 4; ++q) acc0[mt][q] = (f32x4)(0.f);

#pragma unroll
    for (int kc = 0; kc < 4; ++kc){
      bf16x8 aH[2], aL[2];
#pragma unroll
      for (int mt = 0; mt < 2; ++mt){
        int row = mt*16 + fcol;
        int off = row*256 + ((kc*64 + a*16) ^ ((row&7)<<4));
        aH[mt] = *(const bf16x8*)((const char*)&AsH[buf][0] + off);
        aL[mt] = *(const bf16x8*)((const char*)&AsL[buf][0] + off);
      }
#pragma unroll
      for (int q = 0; q < 4; ++q)
#pragma unroll
        for (int mt = 0; mt < 2; ++mt)
          acc0[mt][q] = __builtin_amdgcn_mfma_f32_16x16x32_bf16(aH[mt], rbH[q][kc], acc0[mt][q], 0, 0, 0);
#pragma unroll
      for (int q = 0; q < 4; ++q)
#pragma unroll
        for (int mt = 0; mt < 2; ++mt)
          acc0[mt][q] = __builtin_amdgcn_mfma_f32_16x16x32_bf16(aL[mt], rbH[q][kc], acc0[mt][q], 0, 0, 0);
#pragma unroll
      for (int q = 0; q < 4; ++q)
#pragma unroll
        for (int mt = 0; mt < 2; ++mt)
          acc0[mt][q] = __builtin_amdgcn_mfma_f32_16x16x32_bf16(aH[mt], rbL[q][kc], acc0[mt][q], 0, 0, 0);
    }

    // ---- epilogue-0: level-A cell, pair-sums -> LDS (swizzled fp32) ----
#pragma unroll
    for (int mt = 0; mt < 2; ++mt){
      float hv[4], cv[4];
#pragma unroll
      for (int rr = 0; rr < 4; ++rr){
        float fv = acc0[mt][0][rr] + B4[0];
        float iv = acc0[mt][1][rr] + B4[1];
        float gv = acc0[mt][2][rr] + B4[2];
        float ov = acc0[mt][3][rr] + B4[3];
        float c = sigf(fv)*cc0[mt][rr] + sigf(iv)*tanhf_(gv);
        float h = sigf(ov)*tanhf_(c);
        hv[rr] = h; cv[rr] = c;
      }
#pragma unroll
      for (int p = 0; p < 2; ++p){
        int row1 = mt*8 + a*2 + p;
        int o1 = row1*512 + ((feat*4) ^ ((row1&7)<<4));
        *(float*)((char*)HsF + o1) = hv[2*p] + hv[2*p+1];
        *(float*)((char*)CsF + o1) = cv[2*p] + cv[2*p+1];
      }
    }
    if (have) swrite(buf^1);
    __syncthreads();

    // ---- MFMA-1: level B over 16 Hs rows ----
    f32x4 acc1[4];
#pragma unroll
    for (int q = 0; q < 4; ++q) acc1[q] = (f32x4)(0.f);

#pragma unroll
    for (int kc = 0; kc < 4; ++kc){
      bf16x8 a1H, a1L;
      {
        int cb = kc*128 + a*32;
        const char* base = (const char*)HsF + fcol*512;
        float av[8];
        *(float4*)&av[0] = *(const float4*)(base + ( cb       ^ ((fcol&7)<<4)));
        *(float4*)&av[4] = *(const float4*)(base + ((cb + 16) ^ ((fcol&7)<<4)));
        unsigned int hp[4], lp[4];
#pragma unroll
        for (int p = 0; p < 4; ++p) split2(av[2*p], av[2*p+1], hp[p], lp[p]);
        uint4 hq = {hp[0],hp[1],hp[2],hp[3]};
        uint4 lq = {lp[0],lp[1],lp[2],lp[3]};
        a1H = *(bf16x8*)&hq;
        a1L = *(bf16x8*)&lq;
      }
#pragma unroll
      for (int q = 0; q < 4; ++q)
        acc1[q] = __builtin_amdgcn_mfma_f32_16x16x32_bf16(a1H, rbH[q][kc], acc1[q], 0, 0, 0);
#pragma unroll
      for (int q = 0; q < 4; ++q)
        acc1[q] = __builtin_amdgcn_mfma_f32_16x16x32_bf16(a1L, rbH[q][kc], acc1[q], 0, 0, 0);
#pragma unroll
      for (int q = 0; q < 4; ++q)
        acc1[q] = __builtin_amdgcn_mfma_f32_16x16x32_bf16(a1H, rbL[q][kc], acc1[q], 0, 0, 0);
    }

    // ---- epilogue-1: level-B cell -> global planes ----
    {
      float hv[4], cv[4];
#pragma unroll
      for (int rr = 0; rr < 4; ++rr){
        int n = a*4 + rr;
        float ccv = *(const float*)((const char*)CsF + n*512 + ((feat*4) ^ ((n&7)<<4)));
        float fv = acc1[0][rr] + B4[0];
        float iv = acc1[1][rr] + B4[1];
        float gv = acc1[2][rr] + B4[2];
        float ov = acc1[3][rr] + B4[3];
        float c = sigf(fv)*ccv + sigf(iv)*tanhf_(gv);
        float h = sigf(ov)*tanhf_(c);
        hv[rr] = h; cv[rr] = c;
      }
#pragma unroll
      for (int p = 0; p < 2; ++p){
        long prow = (long)tile*8 + a*2 + p;
        float hs = hv[2*p] + hv[2*p+1];
        unsigned short hi = bf16_rne(hs);
        HpO[prow*HH + feat] = hi;
        LpO[prow*HH + feat] = bf16_trunc(hs - bf16_to_f(hi));
        csO[prow*HH + feat] = cv[2*p] + cv[2*p+1];
      }
    }
    __syncthreads();
    buf ^= 1;
  }
}

// ---------------- multi-level tail block (generic) --------------------------
template<int ROWS0, int NLEV, int INPLANES, int FINAL>
__global__ __launch_bounds__(NT, 2) void treeblk2(
    const unsigned short* __restrict__ Hp, const unsigned short* __restrict__ Lp,
    const float* __restrict__ cs,
    const float* __restrict__ hraw, const float* __restrict__ craw,
    const unsigned short* __restrict__ packH, const unsigned short* __restrict__ packL,
    const float* __restrict__ bias,
    float* __restrict__ h_out, float* __restrict__ c_out,
    float* __restrict__ root_out)
{
  constexpr int MT = (ROWS0 >= 16) ? (ROWS0/16) : 1;
  __shared__ float Asum[ROWS0][132];
  __shared__ float Csum[ROWS0][132];

  const int t = threadIdx.x;
  const long blk = blockIdx.x;
  const int w = t >> 6, l = t & 63;
  const int a = l >> 4, fcol = l & 15, feat = w*16 + fcol;

  {
    constexpr int EPT = ROWS0*HH/NT;
    constexpr int TPR = HH/EPT;
    int row = t/TPR, c0 = (t%TPR)*EPT;
    if (INPLANES){
      long base = (blk*ROWS0 + row)*(long)HH + c0;
#pragma unroll
      for (int j = 0; j < EPT; ++j){
        Asum[row][c0+j] = bf16_to_f(Hp[base+j]) + bf16_to_f(Lp[base+j]);
        Csum[row][c0+j] = cs[base+j];
      }
    } else {
      long g = (blk*2*ROWS0 + 2*row)*(long)HH + c0;
#pragma unroll
      for (int j = 0; j < EPT; ++j){
        Asum[row][c0+j] = hraw[g+j] + hraw[g+HH+j];
        Csum[row][c0+j] = craw[g+j] + craw[g+HH+j];
      }
    }
  }

  bf16x8 rbH[4][4], rbL[4][4];
#pragma unroll
  for (int q = 0; q < 4; ++q)
#pragma unroll
    for (int kc = 0; kc < 4; ++kc){
      long off = ((long)((((w>>1)*8) + q*2 + (w&1))*4 + kc)*64 + l)*8;
      rbH[q][kc] = *(const bf16x8*)&packH[off];
      rbL[q][kc] = *(const bf16x8*)&packL[off];
    }
  float B4[4];
#pragma unroll
  for (int q = 0; q < 4; ++q) B4[q] = bias[q*HH + feat];

  __syncthreads();

#pragma unroll
  for (int lv = 0; lv < NLEV; ++lv){
    const int rows  = ROWS0 >> lv;
    const int tiles = (rows >= 16) ? (rows/16) : 1;
    float hv[MT][4], cv[MT][4];

#pragma unroll
    for (int mt = 0; mt < MT; ++mt){
      if (mt >= tiles) continue;
      bf16x8 aH[4], aL[4];
#pragma unroll
      for (int kc = 0; kc < 4; ++kc){
        const float* ap = &Asum[mt*16 + fcol][kc*32 + a*8];
        float av[8];
        *(float4*)&av[0] = *(const float4*)&ap[0];
        *(float4*)&av[4] = *(const float4*)&ap[4];
        unsigned int hp[4], lp[4];
#pragma unroll
        for (int p = 0; p < 4; ++p) split2(av[2*p], av[2*p+1], hp[p], lp[p]);
        uint4 hq = {hp[0],hp[1],hp[2],hp[3]};
        uint4 lq = {lp[0],lp[1],lp[2],lp[3]};
        aH[kc] = *(bf16x8*)&hq;
        aL[kc] = *(bf16x8*)&lq;
      }
      f32x4 acc[4];
#pragma unroll
      for (int q = 0; q < 4; ++q) acc[q] = (f32x4)(0.f);
#pragma unroll
      for (int kc = 0; kc < 4; ++kc){
#pragma unroll
        for (int q = 0; q < 4; ++q)
          acc[q] = __builtin_amdgcn_mfma_f32_16x16x32_bf16(aH[kc], rbH[q][kc], acc[q], 0, 0, 0);
#pragma unroll
        for (int q = 0; q < 4; ++q)
          acc[q] = __builtin_amdgcn_mfma_f32_16x16x32_bf16(aL[kc], rbH[q][kc], acc[q], 0, 0, 0);
#pragma unroll
        for (int q = 0; q < 4; ++q)
          acc[q] = __builtin_amdgcn_mfma_f32_16x16x32_bf16(aH[kc], rbL[q][kc], acc[q], 0, 0, 0);
      }
#pragma unroll
      for (int rr = 0; rr < 4; ++rr){
        int n = mt*16 + a*4 + rr;
        float ccv = Csum[n][feat];
        float fv = acc[0][rr] + B4[0];
        float iv = acc[1][rr] + B4[1];
        float gv = acc[2][rr] + B4[2];
        float ov = acc[3][rr] + B4[3];
        float c = sigf(fv)*ccv + sigf(iv)*tanhf_(gv);
        float h = sigf(ov)*tanhf_(c);
        hv[mt][rr] = h; cv[mt][rr] = c;
      }
    }
    __syncthreads();

    if (lv < NLEV-1){
#pragma unroll
      for (int mt = 0; mt < MT; ++mt){
        if (mt >= tiles) continue;
#pragma unroll
        for (int p = 0; p < 2; ++p){
          int n0 = mt*16 + a*4 + 2*p;
          if (n0 < rows){
            int prow = n0 >> 1;
            Asum[prow][feat] = hv[mt][2*p] + hv[mt][2*p+1];
            Csum[prow][feat] = cv[mt][2*p] + cv[mt][2*p+1];
          }
        }
      }
      __syncthreads();
    } else if (FINAL){
      if (a == 0) root_out[feat] = hv[0][0];
    } else {
      if (a == 0){
        h_out[blk*HH + feat] = hv[0][0];
        c_out[blk*HH + feat] = cv[0][0];
      }
    }
  }
}

extern "C" void kernel_launch(void* const* d_in, const int* in_sizes, int n_in,
                              void* d_out, int out_size, void* d_ws, size_t ws_size,
                              hipStream_t stream){
  const float* leaf = (const float*)d_in[0];   // 131072 x 128 f32
  const float* W    = (const float*)d_in[1];   // 512 x 256 f32
  const float* bias = (const float*)d_in[2];   // 512 f32
  float* out = (float*)d_out;                  // 128 f32

  unsigned short* pEh = (unsigned short*)d_ws;      // 65536 u16 each
  unsigned short* pEl = pEh + 65536;
  unsigned short* pLh = pEl + 65536;
  unsigned short* pLl = pLh + 65536;
  unsigned short* HpA = pLl + 65536;                // 2^16 x 128 u16
  unsigned short* LpA = HpA + (1l<<16)*HH;
  unsigned short* HpB = LpA + (1l<<16)*HH;          // 2^14 x 128 u16
  unsigned short* LpB = HpB + (1l<<14)*HH;
  float* csA = (float*)(LpB + (1l<<14)*HH);         // 2^16 x 128 f32
  float* csB = csA + (1l<<16)*HH;                   // 2^14 x 128 f32
  float* h32 = csB + (1l<<14)*HH;                   // 32 x 128 f32
  float* c32 = h32 + 32*HH;

  prep_pack<<<32, PT, 0, stream>>>(W, pEh, pEl, pLh, pLl);

  // L0: 2^17 leaves -> 2^16 pair-rows
  leafK<<<512, NT, 0, stream>>>(leaf, pLh, pLl, bias, HpA, LpA, csA, 4096);
  // L1+L2: 2^16 rows -> 2^14
  fuse2<<<512, NT, 0, stream>>>(HpA, LpA, csA, pEh, pEl, bias, HpB, LpB, csB, 2048);
  // L3+L4: 2^14 -> 2^12
  fuse2<<<512, NT, 0, stream>>>(HpB, LpB, csB, pEh, pEl, bias, HpA, LpA, csA, 512);
  // L5+L6: 2^12 -> 2^10
  fuse2<<<128, NT, 0, stream>>>(HpA, LpA, csA, pEh, pEl, bias, HpB, LpB, csB, 128);
  // L7..L12: 2^10 pair-rows -> 32 raw nodes
  treeblk2<32,6,1,0><<<32, NT, 0, stream>>>(HpB, LpB, csB, nullptr, nullptr,
                                            pEh, pEl, bias, h32, c32, nullptr);
  // L13..L17: 32 raw children -> root
  treeblk2<16,5,0,1><<<1, NT, 0, stream>>>(nullptr, nullptr, nullptr, h32, c32,
                                           pEh, pEl, bias, nullptr, nullptr, out);

  (void)in_sizes; (void)n_in; (void)out_size; (void)ws_size;
}

// Round 9
// 138.870 us; speedup vs baseline: 2.2420x; 1.0292x over previous
//
#include <hip/hip_runtime.h>

#define HH 128
#define NT 512
#define PT 256

typedef float  f32x4  __attribute__((ext_vector_type(4)));
typedef short  bf16x8 __attribute__((ext_vector_type(8)));

static __device__ __forceinline__ unsigned short bf16_rne(float f){
  unsigned int u = __float_as_uint(f);
  unsigned int r = u + 0x7fffu + ((u >> 16) & 1u);
  return (unsigned short)(r >> 16);
}
static __device__ __forceinline__ unsigned short bf16_trunc(float f){
  return (unsigned short)(__float_as_uint(f) >> 16);
}
static __device__ __forceinline__ float bf16_to_f(unsigned short s){
  return __uint_as_float(((unsigned int)s) << 16);
}
// split two fp32 into packed hi-bf16 u32 and lo-bf16 u32 (elem0 in low16)
static __device__ __forceinline__ void split2(float x0, float x1,
                                              unsigned int& hp, unsigned int& lp){
  unsigned int u0 = __float_as_uint(x0), u1 = __float_as_uint(x1);
  unsigned int r0 = u0 + 0x7fffu + ((u0>>16)&1u);
  unsigned int r1 = u1 + 0x7fffu + ((u1>>16)&1u);
  float l0 = x0 - __uint_as_float(r0 & 0xffff0000u);
  float l1 = x1 - __uint_as_float(r1 & 0xffff0000u);
  hp = __builtin_amdgcn_perm(r1, r0, 0x07060302u);
  lp = __builtin_amdgcn_perm(__float_as_uint(l1), __float_as_uint(l0), 0x07060302u);
}

__device__ __forceinline__ float sigf(float x){
  float t = __builtin_amdgcn_exp2f(-1.44269504089f * x);
  return __builtin_amdgcn_rcpf(1.f + t);
}
__device__ __forceinline__ float tanhf_(float x){
  float t = __builtin_amdgcn_exp2f(2.88539008178f * x);
  return 1.f - 2.f*__builtin_amdgcn_rcpf(t + 1.f);
}

// Pack W into MFMA-B-fragment order, split bf16 hi/lo.
__global__ __launch_bounds__(PT) void prep_pack(
    const float* __restrict__ W,
    unsigned short* __restrict__ pEh, unsigned short* __restrict__ pEl,
    unsigned short* __restrict__ pLh, unsigned short* __restrict__ pLl)
{
  int idx = blockIdx.x*PT + threadIdx.x;     // 0..8191
  int l  = idx & 63;
  int kc = (idx >> 6) & 3;
  int gl = (idx >> 8) & 7;
  int wp = (idx >> 11);                      // 0..3
  int q  = gl >> 1, ft = gl & 1;
  int g  = q*128 + wp*32 + ft*16 + (l & 15);
  int kbase = kc*32 + (l >> 4)*8;

  unsigned short eh[8], el[8], lh[8], ll[8];
#pragma unroll
  for (int j = 0; j < 8; ++j){
    int k = kbase + j;
    float w0 = W[g*256 + k];
    float w1 = W[g*256 + 128 + k];
    float we = w0 + 0.5f*w1;
    unsigned short h0 = bf16_rne(we);
    eh[j] = h0; el[j] = bf16_trunc(we - bf16_to_f(h0));
    unsigned short h1 = bf16_rne(w1);
    lh[j] = h1; ll[j] = bf16_trunc(w1 - bf16_to_f(h1));
  }
  long base = (long)idx*8;
  *(bf16x8*)&pEh[base] = *(bf16x8*)eh;
  *(bf16x8*)&pEl[base] = *(bf16x8*)el;
  *(bf16x8*)&pLh[base] = *(bf16x8*)lh;
  *(bf16x8*)&pLl[base] = *(bf16x8*)ll;
}

// ---------------- leaf kernel: L0 only, forced-resident leaf-B --------------
__global__ __launch_bounds__(NT, 2) void leafK(
    const float* __restrict__ x_leaf,
    const unsigned short* __restrict__ pLh, const unsigned short* __restrict__ pLl,
    const float* __restrict__ bias,
    unsigned short* __restrict__ HpO, unsigned short* __restrict__ LpO,
    float* __restrict__ csO, int ntiles)
{
  __shared__ unsigned short AsH[2][32*HH];
  __shared__ unsigned short AsL[2][32*HH];

  const int t = threadIdx.x, w = t>>6, l = t&63;
  const int a = l>>4, fcol = l&15, feat = w*16 + fcol;

  // resident leaf-B (gates i,g,o = q 1..3): 96 VGPRs, pinned in-loop
  bf16x8 rbH[3][4], rbL[3][4];
#pragma unroll
  for (int qq = 0; qq < 3; ++qq)
#pragma unroll
    for (int kc = 0; kc < 4; ++kc){
      long off = ((long)((((w>>1)*8) + (qq+1)*2 + (w&1))*4 + kc)*64 + l)*8;
      rbH[qq][kc] = *(const bf16x8*)&pLh[off];
      rbL[qq][kc] = *(const bf16x8*)&pLl[off];
    }
  const float Bi = bias[HH + feat], Bg = bias[2*HH + feat], Bo = bias[3*HH + feat];

  const int srow = t>>4, sci = t&15;
  float sv[8];
  auto sload = [&](int tile){
    long base = ((long)tile*32 + srow)*HH + sci*8;
    *(float4*)&sv[0] = *(const float4*)&x_leaf[base];
    *(float4*)&sv[4] = *(const float4*)&x_leaf[base+4];
  };
  auto swrite = [&](int buf){
    unsigned int hp[4], lp[4];
#pragma unroll
    for (int p = 0; p < 4; ++p) split2(sv[2*p], sv[2*p+1], hp[p], lp[p]);
    uint4 hq = {hp[0],hp[1],hp[2],hp[3]};
    uint4 lq = {lp[0],lp[1],lp[2],lp[3]};
    int off = srow*256 + ((sci*16) ^ ((srow&7)<<4));
    *(uint4*)((char*)&AsH[buf][0] + off) = hq;
    *(uint4*)((char*)&AsL[buf][0] + off) = lq;
  };

  int tile = blockIdx.x;
  if (tile < ntiles){ sload(tile); swrite(0); }
  __syncthreads();
  int buf = 0;

  for (; tile < ntiles; tile += gridDim.x){
    // PIN: make B fragments loop-carried so the compiler cannot sink the
    // loads into the loop (R8: VGPR=80 proved it re-loads from L2 per tile).
#pragma unroll
    for (int qq = 0; qq < 3; ++qq)
#pragma unroll
      for (int kc = 0; kc < 4; ++kc){
        asm volatile("" : "+v"(rbH[qq][kc]));
        asm volatile("" : "+v"(rbL[qq][kc]));
      }

    int nxt = tile + gridDim.x;
    bool have = nxt < ntiles;
    if (have) sload(nxt);   // loads in flight under MFMA

    f32x4 acc[2][3];
#pragma unroll
    for (int mt = 0; mt < 2; ++mt)
#pragma unroll
      for (int qq = 0; qq < 3; ++qq) acc[mt][qq] = (f32x4)(0.f);

#pragma unroll
    for (int kc = 0; kc < 4; ++kc){
      bf16x8 aH[2], aL[2];
#pragma unroll
      for (int mt = 0; mt < 2; ++mt){
        int row = mt*16 + fcol;
        int off = row*256 + ((kc*64 + a*16) ^ ((row&7)<<4));
        aH[mt] = *(const bf16x8*)((const char*)&AsH[buf][0] + off);
        aL[mt] = *(const bf16x8*)((const char*)&AsL[buf][0] + off);
      }
#pragma unroll
      for (int qq = 0; qq < 3; ++qq)
#pragma unroll
        for (int mt = 0; mt < 2; ++mt)
          acc[mt][qq] = __builtin_amdgcn_mfma_f32_16x16x32_bf16(aH[mt], rbH[qq][kc], acc[mt][qq], 0, 0, 0);
#pragma unroll
      for (int qq = 0; qq < 3; ++qq)
#pragma unroll
        for (int mt = 0; mt < 2; ++mt)
          acc[mt][qq] = __builtin_amdgcn_mfma_f32_16x16x32_bf16(aL[mt], rbH[qq][kc], acc[mt][qq], 0, 0, 0);
#pragma unroll
      for (int qq = 0; qq < 3; ++qq)
#pragma unroll
        for (int mt = 0; mt < 2; ++mt)
          acc[mt][qq] = __builtin_amdgcn_mfma_f32_16x16x32_bf16(aH[mt], rbL[qq][kc], acc[mt][qq], 0, 0, 0);
    }

    // epilogue (cc = 0)
#pragma unroll
    for (int mt = 0; mt < 2; ++mt){
      float hv[4], cv[4];
#pragma unroll
      for (int rr = 0; rr < 4; ++rr){
        float iv = acc[mt][0][rr] + Bi;
        float gv = acc[mt][1][rr] + Bg;
        float ov = acc[mt][2][rr] + Bo;
        float c = sigf(iv)*tanhf_(gv);
        float h = sigf(ov)*tanhf_(c);
        hv[rr] = h; cv[rr] = c;
      }
#pragma unroll
      for (int p = 0; p < 2; ++p){
        long prow = (long)tile*16 + mt*8 + a*2 + p;
        float hs = hv[2*p] + hv[2*p+1];
        unsigned short hi = bf16_rne(hs);
        HpO[prow*HH + feat] = hi;
        LpO[prow*HH + feat] = bf16_trunc(hs - bf16_to_f(hi));
        csO[prow*HH + feat] = cv[2*p] + cv[2*p+1];
      }
    }

    if (have) swrite(buf^1);
    __syncthreads();
    buf ^= 1;
  }
}

// ---------------- fused 2-level internal kernel, forced-resident eff-B ------
__global__ __launch_bounds__(NT, 2) void fuse2(
    const unsigned short* __restrict__ hPH, const unsigned short* __restrict__ hPL,
    const float* __restrict__ cP,
    const unsigned short* __restrict__ pEh, const unsigned short* __restrict__ pEl,
    const float* __restrict__ bias,
    unsigned short* __restrict__ HpO, unsigned short* __restrict__ LpO,
    float* __restrict__ csO, int ntiles)
{
  __shared__ unsigned short AsH[2][32*HH];
  __shared__ unsigned short AsL[2][32*HH];
  __shared__ float HsF[16*HH];
  __shared__ float CsF[16*HH];

  const int t = threadIdx.x, w = t>>6, l = t&63;
  const int a = l>>4, fcol = l&15, feat = w*16 + fcol;

  bf16x8 rbH[4][4], rbL[4][4];
#pragma unroll
  for (int q = 0; q < 4; ++q)
#pragma unroll
    for (int kc = 0; kc < 4; ++kc){
      long off = ((long)((((w>>1)*8) + q*2 + (w&1))*4 + kc)*64 + l)*8;
      rbH[q][kc] = *(const bf16x8*)&pEh[off];
      rbL[q][kc] = *(const bf16x8*)&pEl[off];
    }
  float B4[4];
#pragma unroll
  for (int q = 0; q < 4; ++q) B4[q] = bias[q*HH + feat];

  const int srow = t>>4, sci = t&15;
  bf16x8 svH, svL;
  auto sload = [&](int tile){
    long base = ((long)tile*32 + srow)*HH + sci*8;
    svH = *(const bf16x8*)&hPH[base];
    svL = *(const bf16x8*)&hPL[base];
  };
  auto swrite = [&](int buf){
    int off = srow*256 + ((sci*16) ^ ((srow&7)<<4));
    *(bf16x8*)((char*)&AsH[buf][0] + off) = svH;
    *(bf16x8*)((char*)&AsL[buf][0] + off) = svL;
  };

  int tile = blockIdx.x;
  if (tile < ntiles){ sload(tile); swrite(0); }
  __syncthreads();
  int buf = 0;

  for (; tile < ntiles; tile += gridDim.x){
    // PIN resident B (see leafK comment)
#pragma unroll
    for (int q = 0; q < 4; ++q)
#pragma unroll
      for (int kc = 0; kc < 4; ++kc){
        asm volatile("" : "+v"(rbH[q][kc]));
        asm volatile("" : "+v"(rbL[q][kc]));
      }

    int nxt = tile + gridDim.x;
    bool have = nxt < ntiles;

    float cc0[2][4];
#pragma unroll
    for (int mt = 0; mt < 2; ++mt)
#pragma unroll
      for (int rr = 0; rr < 4; ++rr)
        cc0[mt][rr] = cP[((long)tile*32 + mt*16 + a*4 + rr)*HH + feat];

    if (have) sload(nxt);

    // ---- MFMA-0: level A over 32 rows ----
    f32x4 acc0[2][4];
#pragma unroll
    for (int mt = 0; mt < 2; ++mt)
#pragma unroll
      for (int q = 0; q < 4; ++q) acc0[mt][q] = (f32x4)(0.f);

#pragma unroll
    for (int kc = 0; kc < 4; ++kc){
      bf16x8 aH[2], aL[2];
#pragma unroll
      for (int mt = 0; mt < 2; ++mt){
        int row = mt*16 + fcol;
        int off = row*256 + ((kc*64 + a*16) ^ ((row&7)<<4));
        aH[mt] = *(const bf16x8*)((const char*)&AsH[buf][0] + off);
        aL[mt] = *(const bf16x8*)((const char*)&AsL[buf][0] + off);
      }
#pragma unroll
      for (int q = 0; q < 4; ++q)
#pragma unroll
        for (int mt = 0; mt < 2; ++mt)
          acc0[mt][q] = __builtin_amdgcn_mfma_f32_16x16x32_bf16(aH[mt], rbH[q][kc], acc0[mt][q], 0, 0, 0);
#pragma unroll
      for (int q = 0; q < 4; ++q)
#pragma unroll
        for (int mt = 0; mt < 2; ++mt)
          acc0[mt][q] = __builtin_amdgcn_mfma_f32_16x16x32_bf16(aL[mt], rbH[q][kc], acc0[mt][q], 0, 0, 0);
#pragma unroll
      for (int q = 0; q < 4; ++q)
#pragma unroll
        for (int mt = 0; mt < 2; ++mt)
          acc0[mt][q] = __builtin_amdgcn_mfma_f32_16x16x32_bf16(aH[mt], rbL[q][kc], acc0[mt][q], 0, 0, 0);
    }

    // ---- epilogue-0 -> LDS pair-sums ----
#pragma unroll
    for (int mt = 0; mt < 2; ++mt){
      float hv[4], cv[4];
#pragma unroll
      for (int rr = 0; rr < 4; ++rr){
        float fv = acc0[mt][0][rr] + B4[0];
        float iv = acc0[mt][1][rr] + B4[1];
        float gv = acc0[mt][2][rr] + B4[2];
        float ov = acc0[mt][3][rr] + B4[3];
        float c = sigf(fv)*cc0[mt][rr] + sigf(iv)*tanhf_(gv);
        float h = sigf(ov)*tanhf_(c);
        hv[rr] = h; cv[rr] = c;
      }
#pragma unroll
      for (int p = 0; p < 2; ++p){
        int row1 = mt*8 + a*2 + p;
        int o1 = row1*512 + ((feat*4) ^ ((row1&7)<<4));
        *(float*)((char*)HsF + o1) = hv[2*p] + hv[2*p+1];
        *(float*)((char*)CsF + o1) = cv[2*p] + cv[2*p+1];
      }
    }
    if (have) swrite(buf^1);
    __syncthreads();

    // ---- MFMA-1: level B over 16 rows ----
    f32x4 acc1[4];
#pragma unroll
    for (int q = 0; q < 4; ++q) acc1[q] = (f32x4)(0.f);

#pragma unroll
    for (int kc = 0; kc < 4; ++kc){
      bf16x8 a1H, a1L;
      {
        int cb = kc*128 + a*32;
        const char* base = (const char*)HsF + fcol*512;
        float av[8];
        *(float4*)&av[0] = *(const float4*)(base + ( cb       ^ ((fcol&7)<<4)));
        *(float4*)&av[4] = *(const float4*)(base + ((cb + 16) ^ ((fcol&7)<<4)));
        unsigned int hp[4], lp[4];
#pragma unroll
        for (int p = 0; p < 4; ++p) split2(av[2*p], av[2*p+1], hp[p], lp[p]);
        uint4 hq = {hp[0],hp[1],hp[2],hp[3]};
        uint4 lq = {lp[0],lp[1],lp[2],lp[3]};
        a1H = *(bf16x8*)&hq;
        a1L = *(bf16x8*)&lq;
      }
#pragma unroll
      for (int q = 0; q < 4; ++q)
        acc1[q] = __builtin_amdgcn_mfma_f32_16x16x32_bf16(a1H, rbH[q][kc], acc1[q], 0, 0, 0);
#pragma unroll
      for (int q = 0; q < 4; ++q)
        acc1[q] = __builtin_amdgcn_mfma_f32_16x16x32_bf16(a1L, rbH[q][kc], acc1[q], 0, 0, 0);
#pragma unroll
      for (int q = 0; q < 4; ++q)
        acc1[q] = __builtin_amdgcn_mfma_f32_16x16x32_bf16(a1H, rbL[q][kc], acc1[q], 0, 0, 0);
    }

    // ---- epilogue-1 -> global planes ----
    {
      float hv[4], cv[4];
#pragma unroll
      for (int rr = 0; rr < 4; ++rr){
        int n = a*4 + rr;
        float ccv = *(const float*)((const char*)CsF + n*512 + ((feat*4) ^ ((n&7)<<4)));
        float fv = acc1[0][rr] + B4[0];
        float iv = acc1[1][rr] + B4[1];
        float gv = acc1[2][rr] + B4[2];
        float ov = acc1[3][rr] + B4[3];
        float c = sigf(fv)*ccv + sigf(iv)*tanhf_(gv);
        float h = sigf(ov)*tanhf_(c);
        hv[rr] = h; cv[rr] = c;
      }
#pragma unroll
      for (int p = 0; p < 2; ++p){
        long prow = (long)tile*8 + a*2 + p;
        float hs = hv[2*p] + hv[2*p+1];
        unsigned short hi = bf16_rne(hs);
        HpO[prow*HH + feat] = hi;
        LpO[prow*HH + feat] = bf16_trunc(hs - bf16_to_f(hi));
        csO[prow*HH + feat] = cv[2*p] + cv[2*p+1];
      }
    }
    __syncthreads();
    buf ^= 1;
  }
}

// ---------------- multi-level tail block (generic) --------------------------
template<int ROWS0, int NLEV, int INPLANES, int FINAL>
__global__ __launch_bounds__(NT, 2) void treeblk2(
    const unsigned short* __restrict__ Hp, const unsigned short* __restrict__ Lp,
    const float* __restrict__ cs,
    const float* __restrict__ hraw, const float* __restrict__ craw,
    const unsigned short* __restrict__ packH, const unsigned short* __restrict__ packL,
    const float* __restrict__ bias,
    float* __restrict__ h_out, float* __restrict__ c_out,
    float* __restrict__ root_out)
{
  constexpr int MT = (ROWS0 >= 16) ? (ROWS0/16) : 1;
  __shared__ float Asum[ROWS0][132];
  __shared__ float Csum[ROWS0][132];

  const int t = threadIdx.x;
  const long blk = blockIdx.x;
  const int w = t >> 6, l = t & 63;
  const int a = l >> 4, fcol = l & 15, feat = w*16 + fcol;

  {
    constexpr int EPT = ROWS0*HH/NT;
    constexpr int TPR = HH/EPT;
    int row = t/TPR, c0 = (t%TPR)*EPT;
    if (INPLANES){
      long base = (blk*ROWS0 + row)*(long)HH + c0;
#pragma unroll
      for (int j = 0; j < EPT; ++j){
        Asum[row][c0+j] = bf16_to_f(Hp[base+j]) + bf16_to_f(Lp[base+j]);
        Csum[row][c0+j] = cs[base+j];
      }
    } else {
      long g = (blk*2*ROWS0 + 2*row)*(long)HH + c0;
#pragma unroll
      for (int j = 0; j < EPT; ++j){
        Asum[row][c0+j] = hraw[g+j] + hraw[g+HH+j];
        Csum[row][c0+j] = craw[g+j] + craw[g+HH+j];
      }
    }
  }

  bf16x8 rbH[4][4], rbL[4][4];
#pragma unroll
  for (int q = 0; q < 4; ++q)
#pragma unroll
    for (int kc = 0; kc < 4; ++kc){
      long off = ((long)((((w>>1)*8) + q*2 + (w&1))*4 + kc)*64 + l)*8;
      rbH[q][kc] = *(const bf16x8*)&packH[off];
      rbL[q][kc] = *(const bf16x8*)&packL[off];
    }
  float B4[4];
#pragma unroll
  for (int q = 0; q < 4; ++q) B4[q] = bias[q*HH + feat];

  __syncthreads();

#pragma unroll
  for (int lv = 0; lv < NLEV; ++lv){
    const int rows  = ROWS0 >> lv;
    const int tiles = (rows >= 16) ? (rows/16) : 1;
    float hv[MT][4], cv[MT][4];

#pragma unroll
    for (int mt = 0; mt < MT; ++mt){
      if (mt >= tiles) continue;
      bf16x8 aH[4], aL[4];
#pragma unroll
      for (int kc = 0; kc < 4; ++kc){
        const float* ap = &Asum[mt*16 + fcol][kc*32 + a*8];
        float av[8];
        *(float4*)&av[0] = *(const float4*)&ap[0];
        *(float4*)&av[4] = *(const float4*)&ap[4];
        unsigned int hp[4], lp[4];
#pragma unroll
        for (int p = 0; p < 4; ++p) split2(av[2*p], av[2*p+1], hp[p], lp[p]);
        uint4 hq = {hp[0],hp[1],hp[2],hp[3]};
        uint4 lq = {lp[0],lp[1],lp[2],lp[3]};
        aH[kc] = *(bf16x8*)&hq;
        aL[kc] = *(bf16x8*)&lq;
      }
      f32x4 acc[4];
#pragma unroll
      for (int q = 0; q < 4; ++q) acc[q] = (f32x4)(0.f);
#pragma unroll
      for (int kc = 0; kc < 4; ++kc){
#pragma unroll
        for (int q = 0; q < 4; ++q)
          acc[q] = __builtin_amdgcn_mfma_f32_16x16x32_bf16(aH[kc], rbH[q][kc], acc[q], 0, 0, 0);
#pragma unroll
        for (int q = 0; q < 4; ++q)
          acc[q] = __builtin_amdgcn_mfma_f32_16x16x32_bf16(aL[kc], rbH[q][kc], acc[q], 0, 0, 0);
#pragma unroll
        for (int q = 0; q < 4; ++q)
          acc[q] = __builtin_amdgcn_mfma_f32_16x16x32_bf16(aH[kc], rbL[q][kc], acc[q], 0, 0, 0);
      }
#pragma unroll
      for (int rr = 0; rr < 4; ++rr){
        int n = mt*16 + a*4 + rr;
        float ccv = Csum[n][feat];
        float fv = acc[0][rr] + B4[0];
        float iv = acc[1][rr] + B4[1];
        float gv = acc[2][rr] + B4[2];
        float ov = acc[3][rr] + B4[3];
        float c = sigf(fv)*ccv + sigf(iv)*tanhf_(gv);
        float h = sigf(ov)*tanhf_(c);
        hv[mt][rr] = h; cv[mt][rr] = c;
      }
    }
    __syncthreads();

    if (lv < NLEV-1){
#pragma unroll
      for (int mt = 0; mt < MT; ++mt){
        if (mt >= tiles) continue;
#pragma unroll
        for (int p = 0; p < 2; ++p){
          int n0 = mt*16 + a*4 + 2*p;
          if (n0 < rows){
            int prow = n0 >> 1;
            Asum[prow][feat] = hv[mt][2*p] + hv[mt][2*p+1];
            Csum[prow][feat] = cv[mt][2*p] + cv[mt][2*p+1];
          }
        }
      }
      __syncthreads();
    } else if (FINAL){
      if (a == 0) root_out[feat] = hv[0][0];
    } else {
      if (a == 0){
        h_out[blk*HH + feat] = hv[0][0];
        c_out[blk*HH + feat] = cv[0][0];
      }
    }
  }
}

extern "C" void kernel_launch(void* const* d_in, const int* in_sizes, int n_in,
                              void* d_out, int out_size, void* d_ws, size_t ws_size,
                              hipStream_t stream){
  const float* leaf = (const float*)d_in[0];   // 131072 x 128 f32
  const float* W    = (const float*)d_in[1];   // 512 x 256 f32
  const float* bias = (const float*)d_in[2];   // 512 f32
  float* out = (float*)d_out;                  // 128 f32

  unsigned short* pEh = (unsigned short*)d_ws;      // 65536 u16 each
  unsigned short* pEl = pEh + 65536;
  unsigned short* pLh = pEl + 65536;
  unsigned short* pLl = pLh + 65536;
  unsigned short* HpA = pLl + 65536;                // 2^16 x 128 u16
  unsigned short* LpA = HpA + (1l<<16)*HH;
  unsigned short* HpB = LpA + (1l<<16)*HH;          // 2^14 x 128 u16
  unsigned short* LpB = HpB + (1l<<14)*HH;
  float* csA = (float*)(LpB + (1l<<14)*HH);         // 2^16 x 128 f32
  float* csB = csA + (1l<<16)*HH;                   // 2^14 x 128 f32
  float* h32 = csB + (1l<<14)*HH;                   // 32 x 128 f32
  float* c32 = h32 + 32*HH;

  prep_pack<<<32, PT, 0, stream>>>(W, pEh, pEl, pLh, pLl);

  // L0: 2^17 leaves -> 2^16 pair-rows
  leafK<<<256, NT, 0, stream>>>(leaf, pLh, pLl, bias, HpA, LpA, csA, 4096);
  // L1+L2: 2^16 rows -> 2^14
  fuse2<<<256, NT, 0, stream>>>(HpA, LpA, csA, pEh, pEl, bias, HpB, LpB, csB, 2048);
  // L3+L4: 2^14 -> 2^12
  fuse2<<<256, NT, 0, stream>>>(HpB, LpB, csB, pEh, pEl, bias, HpA, LpA, csA, 512);
  // L5+L6: 2^12 -> 2^10
  fuse2<<<128, NT, 0, stream>>>(HpA, LpA, csA, pEh, pEl, bias, HpB, LpB, csB, 128);
  // L7..L12: 2^10 pair-rows -> 32 raw nodes
  treeblk2<32,6,1,0><<<32, NT, 0, stream>>>(HpB, LpB, csB, nullptr, nullptr,
                                            pEh, pEl, bias, h32, c32, nullptr);
  // L13..L17: 32 raw children -> root
  treeblk2<16,5,0,1><<<1, NT, 0, stream>>>(nullptr, nullptr, nullptr, h32, c32,
                                           pEh, pEl, bias, nullptr, nullptr, out);

  (void)in_sizes; (void)n_in; (void)out_size; (void)ws_size;
}